// Round 8
// baseline (455.041 us; speedup 1.0000x reference)
//
#include <hip/hip_runtime.h>

// FISSA forward, MI355X. One workgroup per batch (B=1024), 512 threads (8
// waves). Register-blocked fp32 GEMMs: lane = column, wave wv owns rows
// {wv+8r}. R8 = R6 (276us, VGPR 64, 3 blocks/CU) + R7's staging merge only:
// c1 staged into s_kt during the Vx phase, c2 into s_c during the h phase.
// 6 barriers/layer. Max 2 accumulator arrays live per phase (VGPR <= ~76;
// the 3-blocks/CU cliff is at 85 VGPR - R7's fused QKV at 88 lost 32%).

#define NB 1024
#define LL 50
#define DD 64
#define LD 68   // x/b row stride: rows 16B-aligned for b128 broadcast
#define LDT 51  // Kx^T row stride: odd -> transposed writes 2-way max
#define LDC 52  // score/c1/c2 row stride: rows 16B-aligned for b128 broadcast
#define NR 7
#define NEGV (-4294967295.0f)

__device__ __forceinline__ float wsum(float v) {
#pragma unroll
  for (int m = 32; m >= 1; m >>= 1) v += __shfl_xor(v, m, 64);
  return v;
}
__device__ __forceinline__ float wmax(float v) {
#pragma unroll
  for (int m = 32; m >= 1; m >>= 1) v = fmaxf(v, __shfl_xor(v, m, 64));
  return v;
}
__device__ __forceinline__ float rowln(float v) {
  float m = wsum(v) * (1.f / 64.f);
  float df = v - m;
  float var = wsum(df * df) * (1.f / 64.f);
  return df / sqrtf(var + 1e-8f);
}
__device__ __forceinline__ float2 ld2(const float* p) {
  return *reinterpret_cast<const float2*>(p);
}
__device__ __forceinline__ float4 ld4(const float* p) {
  return *reinterpret_cast<const float4*>(p);
}

__global__ __launch_bounds__(512, 2) void fissa_kernel(
    const int* __restrict__ user_items, const int* __restrict__ pos_items,
    const int* __restrict__ neg_items, const float* __restrict__ pmask,
    const float* __restrict__ item_emb, const float* __restrict__ pos_emb,
    const float* __restrict__ Qs, const float* __restrict__ Ks,
    const float* __restrict__ Vs, const float* __restrict__ c1w,
    const float* __restrict__ c1b, const float* __restrict__ c2w,
    const float* __restrict__ c2b, const float* __restrict__ query,
    const float* __restrict__ Klba, const float* __restrict__ Vlba,
    const float* __restrict__ l1w, const float* __restrict__ l1b,
    const float* __restrict__ l2w, const float* __restrict__ l2b,
    const float* __restrict__ gw, const float* __restrict__ gb,
    float* __restrict__ out) {
  __shared__ __align__(16) float s_x[LL * LD];        // x / att / ff (in-place)
  __shared__ __align__(16) float s_b[LL * LD];        // Qx -> Vx -> h (and LBA-Vx)
  __shared__ __align__(16) float s_kt[DD * LDT + 64]; // Kx^T, then c1 (stride LDC)
  __shared__ __align__(16) float s_c[LL * LDC];       // scores -> c2
  __shared__ __align__(16) float s_mask[64], s_qv[64], s_glo[64], s_sm[64],
      s_bias[64], s_bias2[64], s_gw[192], s_scal[2];

  const int b = blockIdx.x;
  const int tid = threadIdx.x;
  const int wv = tid >> 6, ln = tid & 63;

  int qrow[NR], qoff[NR], coff[NR];
  bool qok[NR];
#pragma unroll
  for (int r = 0; r < NR; ++r) {
    int q = wv + 8 * r;
    qok[r] = (q < LL);
    qrow[r] = qok[r] ? q : (LL - 1);
    qoff[r] = qrow[r] * LD;
    coff[r] = qrow[r] * LDC;
  }

  // ---- small params ----
  if (tid < 64) s_mask[tid] = (tid < LL) ? pmask[b * LL + tid] : 0.f;
  else if (tid < 128) s_qv[tid - 64] = query[tid - 64];
  else if (tid < 320) s_gw[tid - 128] = gw[tid - 128];

  // ---- gather + pos emb + mask + LN -> s_x ----
#pragma unroll
  for (int r = 0; r < NR; ++r) {
    int l = qrow[r];
    int u = user_items[b * LL + l];
    float mk = pmask[b * LL + l];
    float v = (item_emb[(size_t)u * DD + ln] + pos_emb[l * DD + ln]) * mk;
    float o = rowln(v);
    if (qok[r]) s_x[qoff[r] + ln] = o;
  }
  __syncthreads();

  // ---- LBA projections: Kx^T -> s_kt, Vx -> s_b (single x-pass) ----
  {
    float akl[NR], avl[NR];
#pragma unroll
    for (int r = 0; r < NR; ++r) { akl[r] = 0.f; avl[r] = 0.f; }
    const float* Kc = Klba + ln;
    const float* Vc = Vlba + ln;
#pragma unroll 2
    for (int kc = 0; kc < DD; kc += 4) {
      float wk0 = Kc[kc * DD], wk1 = Kc[(kc + 1) * DD];
      float wk2 = Kc[(kc + 2) * DD], wk3 = Kc[(kc + 3) * DD];
      float wv0 = Vc[kc * DD], wv1 = Vc[(kc + 1) * DD];
      float wv2 = Vc[(kc + 2) * DD], wv3 = Vc[(kc + 3) * DD];
#pragma unroll
      for (int r = 0; r < NR; ++r) {
        float4 xv = ld4(&s_x[qoff[r] + kc]);
        akl[r] = fmaf(xv.x, wk0, fmaf(xv.y, wk1, fmaf(xv.z, wk2, fmaf(xv.w, wk3, akl[r]))));
        avl[r] = fmaf(xv.x, wv0, fmaf(xv.y, wv1, fmaf(xv.z, wv2, fmaf(xv.w, wv3, avl[r]))));
      }
    }
#pragma unroll
    for (int r = 0; r < NR; ++r)
      if (qok[r]) {
        s_kt[ln * LDT + qrow[r]] = akl[r];
        s_b[qoff[r] + ln] = avl[r];
      }
  }
  __syncthreads();

  // ---- single-wave glo stage ----
  if (wv == 0) {
    float sc = -INFINITY;
    {
      float acc = 0.f;
#pragma unroll 4
      for (int d = 0; d < DD; ++d) acc = fmaf(s_qv[d], s_kt[d * LDT + ln], acc);
      sc = acc;
      if (ln >= LL || s_mask[ln] == 0.f) sc = (ln < LL) ? NEGV : -INFINITY;
    }
    float mx = wmax(sc);
    float e = (ln < LL) ? expf(sc - mx) : 0.f;
    float den = wsum(e);
    if (ln < LL) s_sm[ln] = e / den;  // softmax probs (same-wave DS ordering)
    float acc = 0.f;
#pragma unroll 2
    for (int l = 0; l < LL; ++l) acc = fmaf(s_sm[l], s_b[l * LD + ln], acc);
    float g = rowln(acc);
    float h = fmaxf(l1w[0] * g + l1b[0], 0.f);
    float glo = rowln(l2w[0] * h + l2b[0] + g);
    s_glo[ln] = glo;
    float gs = wsum(glo * s_gw[64 + ln]);
    if (ln == 0) s_scal[0] = gs + gb[0];
  }
  __syncthreads();

  // ---- SAB layers ----
#pragma unroll 1
  for (int i = 0; i < 2; ++i) {
    const float* Qc = Qs + i * DD * DD + ln;
    const float* Kc = Ks + i * DD * DD + ln;
    const float* Vc = Vs + i * DD * DD + ln;

    // -- Qx -> s_b, Kx^T -> s_kt (two accumulator arrays, as R6) --
    {
      float aq[NR], ak[NR];
#pragma unroll
      for (int r = 0; r < NR; ++r) { aq[r] = 0.f; ak[r] = 0.f; }
#pragma unroll 2
      for (int kc = 0; kc < DD; kc += 4) {
        float wq0 = Qc[kc * DD], wq1 = Qc[(kc + 1) * DD];
        float wq2 = Qc[(kc + 2) * DD], wq3 = Qc[(kc + 3) * DD];
        float wk0 = Kc[kc * DD], wk1 = Kc[(kc + 1) * DD];
        float wk2 = Kc[(kc + 2) * DD], wk3 = Kc[(kc + 3) * DD];
#pragma unroll
        for (int r = 0; r < NR; ++r) {
          float4 xv = ld4(&s_x[qoff[r] + kc]);
          aq[r] = fmaf(xv.x, wq0, fmaf(xv.y, wq1, fmaf(xv.z, wq2, fmaf(xv.w, wq3, aq[r]))));
          ak[r] = fmaf(xv.x, wk0, fmaf(xv.y, wk1, fmaf(xv.z, wk2, fmaf(xv.w, wk3, ak[r]))));
        }
      }
#pragma unroll
      for (int r = 0; r < NR; ++r)
        if (qok[r]) {
          s_b[qoff[r] + ln] = aq[r];
          s_kt[ln * LDT + qrow[r]] = ak[r];
        }
    }
    __syncthreads();

    // -- scores -> s_c (Qx b128 broadcasts, Kx^T stride-1 lane reads) --
    {
      float sc[NR];
#pragma unroll
      for (int r = 0; r < NR; ++r) sc[r] = 0.f;
#pragma unroll 2
      for (int dc = 0; dc < DD; dc += 4) {
        float k0 = s_kt[dc * LDT + ln];
        float k1 = s_kt[(dc + 1) * LDT + ln];
        float k2 = s_kt[(dc + 2) * LDT + ln];
        float k3 = s_kt[(dc + 3) * LDT + ln];
#pragma unroll
        for (int r = 0; r < NR; ++r) {
          float4 qv = ld4(&s_b[qoff[r] + dc]);
          sc[r] = fmaf(qv.x, k0, fmaf(qv.y, k1, fmaf(qv.z, k2, fmaf(qv.w, k3, sc[r]))));
        }
      }
      if (ln < LL) {
        float mk = s_mask[ln];
#pragma unroll
        for (int r = 0; r < NR; ++r)
          if (qok[r]) {
            float v = sc[r] * 0.125f;     // / sqrt(64)
            if (ln > qrow[r]) v = NEGV;   // causal
            if (mk == 0.f) v = NEGV;      // key mask
            v *= s_mask[qrow[r]];         // * padding_mask[q]
            s_c[coff[r] + ln] = v;
          }
      }
    }
    __syncthreads();

    // -- Vx -> s_b (Qx dead); stage c1 -> s_kt (Kx^T dead) + biases --
    {
      float av[NR];
#pragma unroll
      for (int r = 0; r < NR; ++r) av[r] = 0.f;
#pragma unroll 2
      for (int kc = 0; kc < DD; kc += 4) {
        float wv0 = Vc[kc * DD], wv1 = Vc[(kc + 1) * DD];
        float wv2 = Vc[(kc + 2) * DD], wv3 = Vc[(kc + 3) * DD];
#pragma unroll
        for (int r = 0; r < NR; ++r) {
          float4 xv = ld4(&s_x[qoff[r] + kc]);
          av[r] = fmaf(xv.x, wv0, fmaf(xv.y, wv1, fmaf(xv.z, wv2, fmaf(xv.w, wv3, av[r]))));
        }
      }
#pragma unroll
      for (int r = 0; r < NR; ++r)
        if (qok[r]) {
          s_b[qoff[r] + ln] = av[r];
          if (ln < LL) s_kt[coff[r] + ln] = c1w[i * LL * LL + qrow[r] * LL + ln];
        }
      if (tid < LL) {
        s_bias[tid] = c1b[i * LL + tid];
        s_bias2[tid] = c2b[i * LL + tid];
      }
    }
    __syncthreads();

    // -- att = scores@Vx + x, LN fused -> s_x --
    {
      float at[NR];
#pragma unroll
      for (int r = 0; r < NR; ++r) at[r] = s_x[qoff[r] + ln];  // residual
#pragma unroll 2
      for (int k = 0; k < 48; k += 4) {
        float v0 = s_b[k * LD + ln];
        float v1 = s_b[(k + 1) * LD + ln];
        float v2 = s_b[(k + 2) * LD + ln];
        float v3 = s_b[(k + 3) * LD + ln];
#pragma unroll
        for (int r = 0; r < NR; ++r) {
          float4 sv = ld4(&s_c[coff[r] + k]);
          at[r] = fmaf(sv.x, v0, fmaf(sv.y, v1, fmaf(sv.z, v2, fmaf(sv.w, v3, at[r]))));
        }
      }
      {
        float v0 = s_b[48 * LD + ln];
        float v1 = s_b[49 * LD + ln];
#pragma unroll
        for (int r = 0; r < NR; ++r) {
          float2 sv = ld2(&s_c[coff[r] + 48]);
          at[r] = fmaf(sv.x, v0, fmaf(sv.y, v1, at[r]));
        }
      }
#pragma unroll
      for (int r = 0; r < NR; ++r) {
        float o = rowln(at[r]);
        if (qok[r]) s_x[qoff[r] + ln] = o;
      }
    }
    __syncthreads();

    // -- h = relu(c1@att + c1b) -> s_b; stage c2 -> s_c (scores dead) --
    {
#pragma unroll
      for (int r = 0; r < NR; ++r)
        if (qok[r] && ln < LL)
          s_c[coff[r] + ln] = c2w[i * LL * LL + qrow[r] * LL + ln];
      float hh[NR];
#pragma unroll
      for (int r = 0; r < NR; ++r) hh[r] = 0.f;
#pragma unroll 2
      for (int j = 0; j < 48; j += 4) {
        float x0 = s_x[j * LD + ln];
        float x1 = s_x[(j + 1) * LD + ln];
        float x2 = s_x[(j + 2) * LD + ln];
        float x3 = s_x[(j + 3) * LD + ln];
#pragma unroll
        for (int r = 0; r < NR; ++r) {
          float4 cv = ld4(&s_kt[coff[r] + j]);
          hh[r] = fmaf(cv.x, x0, fmaf(cv.y, x1, fmaf(cv.z, x2, fmaf(cv.w, x3, hh[r]))));
        }
      }
      {
        float x0 = s_x[48 * LD + ln];
        float x1 = s_x[49 * LD + ln];
#pragma unroll
        for (int r = 0; r < NR; ++r) {
          float2 cv = ld2(&s_kt[coff[r] + 48]);
          hh[r] = fmaf(cv.x, x0, fmaf(cv.y, x1, hh[r]));
        }
      }
#pragma unroll
      for (int r = 0; r < NR; ++r)
        if (qok[r]) s_b[qoff[r] + ln] = fmaxf(hh[r] + s_bias[qrow[r]], 0.f);
    }
    __syncthreads();

    // -- ff = c2@h + c2b + att, *mask, LN fused -> s_x --
    {
      float f0[NR];
#pragma unroll
      for (int r = 0; r < NR; ++r) f0[r] = s_x[qoff[r] + ln];  // att residual
#pragma unroll 2
      for (int j = 0; j < 48; j += 4) {
        float h0 = s_b[j * LD + ln];
        float h1 = s_b[(j + 1) * LD + ln];
        float h2 = s_b[(j + 2) * LD + ln];
        float h3 = s_b[(j + 3) * LD + ln];
#pragma unroll
        for (int r = 0; r < NR; ++r) {
          float4 cv = ld4(&s_c[coff[r] + j]);
          f0[r] = fmaf(cv.x, h0, fmaf(cv.y, h1, fmaf(cv.z, h2, fmaf(cv.w, h3, f0[r]))));
        }
      }
      {
        float h0 = s_b[48 * LD + ln];
        float h1 = s_b[49 * LD + ln];
#pragma unroll
        for (int r = 0; r < NR; ++r) {
          float2 cv = ld2(&s_c[coff[r] + 48]);
          f0[r] = fmaf(cv.x, h0, fmaf(cv.y, h1, f0[r]));
        }
      }
#pragma unroll
      for (int r = 0; r < NR; ++r) {
        float v = (f0[r] + s_bias2[qrow[r]]) * s_mask[qrow[r]];
        float o = rowln(v);
        if (qok[r]) s_x[qoff[r] + ln] = o;
      }
    }
    __syncthreads();
  }

  // ---- gating + output: one wave per (pos/neg, l) row ----
  float g2c = s_scal[0];
  float gloc = s_glo[ln];
#pragma unroll 1
  for (int row = wv; row < 2 * LL; row += 8) {
    int sgn = row >= LL;
    int l = row - sgn * LL;
    int u = user_items[b * LL + l];
    int it = sgn ? neg_items[b * LL + l] : pos_items[b * LL + l];
    float ie_d = item_emb[(size_t)u * DD + ln];
    float mi_d = item_emb[(size_t)it * DD + ln];
    float logit = wsum(ie_d * s_gw[ln] + mi_d * s_gw[128 + ln]) + g2c;
    float sg = 1.f / (1.f + expf(-logit));
    float g = 1.f / (1.f + expf(-sg));  // sigmoid(sigmoid(logit))
    float od = (s_x[l * LD + ln] * g + gloc * (1.f - g)) * s_mask[l];
    float o = rowln(od);
    float res = wsum(o * mi_d);
    if (ln == 0) out[(sgn * NB + b) * LL + l] = res;
  }
}

extern "C" void kernel_launch(void* const* d_in, const int* in_sizes, int n_in,
                              void* d_out, int out_size, void* d_ws, size_t ws_size,
                              hipStream_t stream) {
  const int* user_items = (const int*)d_in[0];
  const int* pos_items = (const int*)d_in[1];
  const int* neg_items = (const int*)d_in[2];
  const float* pmask = (const float*)d_in[3];
  const float* item_emb = (const float*)d_in[4];
  const float* pos_emb = (const float*)d_in[5];
  const float* Qs = (const float*)d_in[6];
  const float* Ks = (const float*)d_in[7];
  const float* Vs = (const float*)d_in[8];
  const float* c1w = (const float*)d_in[9];
  const float* c1b = (const float*)d_in[10];
  const float* c2w = (const float*)d_in[11];
  const float* c2b = (const float*)d_in[12];
  const float* query = (const float*)d_in[13];
  const float* Klba = (const float*)d_in[14];
  const float* Vlba = (const float*)d_in[15];
  const float* l1w = (const float*)d_in[16];
  const float* l1b = (const float*)d_in[17];
  const float* l2w = (const float*)d_in[18];
  const float* l2b = (const float*)d_in[19];
  const float* gw = (const float*)d_in[20];
  const float* gb = (const float*)d_in[21];
  float* out = (float*)d_out;

  fissa_kernel<<<dim3(NB), dim3(512), 0, stream>>>(
      user_items, pos_items, neg_items, pmask, item_emb, pos_emb, Qs, Ks, Vs,
      c1w, c1b, c2w, c2b, query, Klba, Vlba, l1w, l1b, l2w, l2b, gw, gb, out);
}

// Round 9
// 355.947 us; speedup vs baseline: 1.2784x; 1.2784x over previous
//
#include <hip/hip_runtime.h>

// FISSA forward, MI355X. R9: one batch per 1024-thread block (16 waves),
// NR=4 rows/wave. Same phase structure + inner loops as R6 (276us best).
// Rationale: R6 at 512 threads had 1024 blocks / (256CU x 3 resident) = 1.33
// rounds -> 25% tail at 1-block/CU. 1024-thread blocks give 2 blocks/CU x 16
// waves = 32 waves/CU (HW cap) and exactly 2.0 residency rounds (no tail).
// NR=4 keeps natural VGPR ~50 (cliff at 64: 8 waves/SIMD needs <=64 VGPR;
// R7/R8 at 72-88 VGPR lost 30%+). LDS 53.2 KB -> 2 blocks/CU within 160 KB.

#define NB 1024
#define NT 1024
#define NW 16
#define LL 50
#define DD 64
#define LD 68   // x/b row stride: rows 16B-aligned for b128 broadcast
#define LDT 51  // Kx^T row stride: odd -> transposed writes 2-way max
#define LDC 52  // score/c1/c2 row stride: rows 16B-aligned for b128 broadcast
#define NR 4
#define NEGV (-4294967295.0f)

__device__ __forceinline__ float wsum(float v) {
#pragma unroll
  for (int m = 32; m >= 1; m >>= 1) v += __shfl_xor(v, m, 64);
  return v;
}
__device__ __forceinline__ float wmax(float v) {
#pragma unroll
  for (int m = 32; m >= 1; m >>= 1) v = fmaxf(v, __shfl_xor(v, m, 64));
  return v;
}
__device__ __forceinline__ float rowln(float v) {
  float m = wsum(v) * (1.f / 64.f);
  float df = v - m;
  float var = wsum(df * df) * (1.f / 64.f);
  return df / sqrtf(var + 1e-8f);
}
__device__ __forceinline__ float2 ld2(const float* p) {
  return *reinterpret_cast<const float2*>(p);
}
__device__ __forceinline__ float4 ld4(const float* p) {
  return *reinterpret_cast<const float4*>(p);
}

__global__ __launch_bounds__(NT, 8) void fissa_kernel(
    const int* __restrict__ user_items, const int* __restrict__ pos_items,
    const int* __restrict__ neg_items, const float* __restrict__ pmask,
    const float* __restrict__ item_emb, const float* __restrict__ pos_emb,
    const float* __restrict__ Qs, const float* __restrict__ Ks,
    const float* __restrict__ Vs, const float* __restrict__ c1w,
    const float* __restrict__ c1b, const float* __restrict__ c2w,
    const float* __restrict__ c2b, const float* __restrict__ query,
    const float* __restrict__ Klba, const float* __restrict__ Vlba,
    const float* __restrict__ l1w, const float* __restrict__ l1b,
    const float* __restrict__ l2w, const float* __restrict__ l2b,
    const float* __restrict__ gw, const float* __restrict__ gb,
    float* __restrict__ out) {
  __shared__ __align__(16) float s_x[LL * LD];        // x / att / ff (in-place)
  __shared__ __align__(16) float s_b[LL * LD];        // Qx -> Vx -> h (and LBA-Vx)
  __shared__ __align__(16) float s_kt[DD * LDT + 64]; // Kx^T
  __shared__ __align__(16) float s_c[LL * LDC];       // scores -> c1 -> c2
  __shared__ __align__(16) float s_mask[64], s_qv[64], s_glo[64], s_sm[64],
      s_bias[64], s_gw[192], s_scal[2];

  const int b = blockIdx.x;
  const int tid = threadIdx.x;
  const int wv = tid >> 6, ln = tid & 63;

  int qrow[NR], qoff[NR], coff[NR];
  bool qok[NR];
#pragma unroll
  for (int r = 0; r < NR; ++r) {
    int q = wv + NW * r;
    qok[r] = (q < LL);
    qrow[r] = qok[r] ? q : (LL - 1);
    qoff[r] = qrow[r] * LD;
    coff[r] = qrow[r] * LDC;
  }

  // ---- small params ----
  if (tid < 64) s_mask[tid] = (tid < LL) ? pmask[b * LL + tid] : 0.f;
  else if (tid < 128) s_qv[tid - 64] = query[tid - 64];
  else if (tid < 320) s_gw[tid - 128] = gw[tid - 128];

  // ---- gather + pos emb + mask + LN -> s_x ----
#pragma unroll
  for (int r = 0; r < NR; ++r) {
    int l = qrow[r];
    int u = user_items[b * LL + l];
    float mk = pmask[b * LL + l];
    float v = (item_emb[(size_t)u * DD + ln] + pos_emb[l * DD + ln]) * mk;
    float o = rowln(v);
    if (qok[r]) s_x[qoff[r] + ln] = o;
  }
  __syncthreads();

  // ---- LBA projections: Kx^T -> s_kt, Vx -> s_b (single x-pass) ----
  {
    float akl[NR], avl[NR];
#pragma unroll
    for (int r = 0; r < NR; ++r) { akl[r] = 0.f; avl[r] = 0.f; }
    const float* Kc = Klba + ln;
    const float* Vc = Vlba + ln;
#pragma unroll 2
    for (int kc = 0; kc < DD; kc += 4) {
      float wk0 = Kc[kc * DD], wk1 = Kc[(kc + 1) * DD];
      float wk2 = Kc[(kc + 2) * DD], wk3 = Kc[(kc + 3) * DD];
      float wv0 = Vc[kc * DD], wv1 = Vc[(kc + 1) * DD];
      float wv2 = Vc[(kc + 2) * DD], wv3 = Vc[(kc + 3) * DD];
#pragma unroll
      for (int r = 0; r < NR; ++r) {
        float4 xv = ld4(&s_x[qoff[r] + kc]);
        akl[r] = fmaf(xv.x, wk0, fmaf(xv.y, wk1, fmaf(xv.z, wk2, fmaf(xv.w, wk3, akl[r]))));
        avl[r] = fmaf(xv.x, wv0, fmaf(xv.y, wv1, fmaf(xv.z, wv2, fmaf(xv.w, wv3, avl[r]))));
      }
    }
#pragma unroll
    for (int r = 0; r < NR; ++r)
      if (qok[r]) {
        s_kt[ln * LDT + qrow[r]] = akl[r];
        s_b[qoff[r] + ln] = avl[r];
      }
  }
  __syncthreads();

  // ---- single-wave glo stage ----
  if (wv == 0) {
    float sc = -INFINITY;
    {
      float acc = 0.f;
#pragma unroll 4
      for (int d = 0; d < DD; ++d) acc = fmaf(s_qv[d], s_kt[d * LDT + ln], acc);
      sc = acc;
      if (ln >= LL || s_mask[ln] == 0.f) sc = (ln < LL) ? NEGV : -INFINITY;
    }
    float mx = wmax(sc);
    float e = (ln < LL) ? expf(sc - mx) : 0.f;
    float den = wsum(e);
    if (ln < LL) s_sm[ln] = e / den;  // softmax probs (same-wave DS ordering)
    float acc = 0.f;
#pragma unroll 2
    for (int l = 0; l < LL; ++l) acc = fmaf(s_sm[l], s_b[l * LD + ln], acc);
    float g = rowln(acc);
    float h = fmaxf(l1w[0] * g + l1b[0], 0.f);
    float glo = rowln(l2w[0] * h + l2b[0] + g);
    s_glo[ln] = glo;
    float gs = wsum(glo * s_gw[64 + ln]);
    if (ln == 0) s_scal[0] = gs + gb[0];
  }
  __syncthreads();

  // ---- SAB layers ----
#pragma unroll 1
  for (int i = 0; i < 2; ++i) {
    const float* Qc = Qs + i * DD * DD + ln;
    const float* Kc = Ks + i * DD * DD + ln;
    const float* Vc = Vs + i * DD * DD + ln;

    // -- Qx -> s_b, Kx^T -> s_kt --
    {
      float aq[NR], ak[NR];
#pragma unroll
      for (int r = 0; r < NR; ++r) { aq[r] = 0.f; ak[r] = 0.f; }
#pragma unroll 2
      for (int kc = 0; kc < DD; kc += 4) {
        float wq0 = Qc[kc * DD], wq1 = Qc[(kc + 1) * DD];
        float wq2 = Qc[(kc + 2) * DD], wq3 = Qc[(kc + 3) * DD];
        float wk0 = Kc[kc * DD], wk1 = Kc[(kc + 1) * DD];
        float wk2 = Kc[(kc + 2) * DD], wk3 = Kc[(kc + 3) * DD];
#pragma unroll
        for (int r = 0; r < NR; ++r) {
          float4 xv = ld4(&s_x[qoff[r] + kc]);
          aq[r] = fmaf(xv.x, wq0, fmaf(xv.y, wq1, fmaf(xv.z, wq2, fmaf(xv.w, wq3, aq[r]))));
          ak[r] = fmaf(xv.x, wk0, fmaf(xv.y, wk1, fmaf(xv.z, wk2, fmaf(xv.w, wk3, ak[r]))));
        }
      }
#pragma unroll
      for (int r = 0; r < NR; ++r)
        if (qok[r]) {
          s_b[qoff[r] + ln] = aq[r];
          s_kt[ln * LDT + qrow[r]] = ak[r];
        }
    }
    __syncthreads();

    // -- scores -> s_c (Qx b128 broadcasts, Kx^T stride-1 lane reads) --
    {
      float sc[NR];
#pragma unroll
      for (int r = 0; r < NR; ++r) sc[r] = 0.f;
#pragma unroll 2
      for (int dc = 0; dc < DD; dc += 4) {
        float k0 = s_kt[dc * LDT + ln];
        float k1 = s_kt[(dc + 1) * LDT + ln];
        float k2 = s_kt[(dc + 2) * LDT + ln];
        float k3 = s_kt[(dc + 3) * LDT + ln];
#pragma unroll
        for (int r = 0; r < NR; ++r) {
          float4 qv = ld4(&s_b[qoff[r] + dc]);
          sc[r] = fmaf(qv.x, k0, fmaf(qv.y, k1, fmaf(qv.z, k2, fmaf(qv.w, k3, sc[r]))));
        }
      }
      if (ln < LL) {
        float mk = s_mask[ln];
#pragma unroll
        for (int r = 0; r < NR; ++r)
          if (qok[r]) {
            float v = sc[r] * 0.125f;     // / sqrt(64)
            if (ln > qrow[r]) v = NEGV;   // causal
            if (mk == 0.f) v = NEGV;      // key mask
            v *= s_mask[qrow[r]];         // * padding_mask[q]
            s_c[coff[r] + ln] = v;
          }
      }
    }
    __syncthreads();

    // -- Vx -> s_b (Qx dead) --
    {
      float av[NR];
#pragma unroll
      for (int r = 0; r < NR; ++r) av[r] = 0.f;
#pragma unroll 2
      for (int kc = 0; kc < DD; kc += 4) {
        float wv0 = Vc[kc * DD], wv1 = Vc[(kc + 1) * DD];
        float wv2 = Vc[(kc + 2) * DD], wv3 = Vc[(kc + 3) * DD];
#pragma unroll
        for (int r = 0; r < NR; ++r) {
          float4 xv = ld4(&s_x[qoff[r] + kc]);
          av[r] = fmaf(xv.x, wv0, fmaf(xv.y, wv1, fmaf(xv.z, wv2, fmaf(xv.w, wv3, av[r]))));
        }
      }
#pragma unroll
      for (int r = 0; r < NR; ++r)
        if (qok[r]) s_b[qoff[r] + ln] = av[r];
    }
    __syncthreads();

    // -- att = scores@Vx + x, LN fused -> s_x --
    {
      float at[NR];
#pragma unroll
      for (int r = 0; r < NR; ++r) at[r] = s_x[qoff[r] + ln];  // residual
#pragma unroll 2
      for (int k = 0; k < 48; k += 4) {
        float v0 = s_b[k * LD + ln];
        float v1 = s_b[(k + 1) * LD + ln];
        float v2 = s_b[(k + 2) * LD + ln];
        float v3 = s_b[(k + 3) * LD + ln];
#pragma unroll
        for (int r = 0; r < NR; ++r) {
          float4 sv = ld4(&s_c[coff[r] + k]);
          at[r] = fmaf(sv.x, v0, fmaf(sv.y, v1, fmaf(sv.z, v2, fmaf(sv.w, v3, at[r]))));
        }
      }
      {
        float v0 = s_b[48 * LD + ln];
        float v1 = s_b[49 * LD + ln];
#pragma unroll
        for (int r = 0; r < NR; ++r) {
          float2 sv = ld2(&s_c[coff[r] + 48]);
          at[r] = fmaf(sv.x, v0, fmaf(sv.y, v1, at[r]));
        }
      }
#pragma unroll
      for (int r = 0; r < NR; ++r) {
        float o = rowln(at[r]);
        if (qok[r]) s_x[qoff[r] + ln] = o;
      }
    }
    __syncthreads();

    // -- stage c1 -> s_c, c1b -> s_bias --
    for (int e = tid; e < LL * LL; e += NT) {
      int q = e / LL;
      s_c[q * LDC + (e - q * LL)] = c1w[i * LL * LL + e];
    }
    if (tid < LL) s_bias[tid] = c1b[i * LL + tid];
    __syncthreads();

    // -- h = relu(c1@att + c1b) -> s_b --
    {
      float hh[NR];
#pragma unroll
      for (int r = 0; r < NR; ++r) hh[r] = 0.f;
#pragma unroll 2
      for (int j = 0; j < 48; j += 4) {
        float x0 = s_x[j * LD + ln];
        float x1 = s_x[(j + 1) * LD + ln];
        float x2 = s_x[(j + 2) * LD + ln];
        float x3 = s_x[(j + 3) * LD + ln];
#pragma unroll
        for (int r = 0; r < NR; ++r) {
          float4 cv = ld4(&s_c[coff[r] + j]);
          hh[r] = fmaf(cv.x, x0, fmaf(cv.y, x1, fmaf(cv.z, x2, fmaf(cv.w, x3, hh[r]))));
        }
      }
      {
        float x0 = s_x[48 * LD + ln];
        float x1 = s_x[49 * LD + ln];
#pragma unroll
        for (int r = 0; r < NR; ++r) {
          float2 cv = ld2(&s_c[coff[r] + 48]);
          hh[r] = fmaf(cv.x, x0, fmaf(cv.y, x1, hh[r]));
        }
      }
#pragma unroll
      for (int r = 0; r < NR; ++r)
        if (qok[r]) s_b[qoff[r] + ln] = fmaxf(hh[r] + s_bias[qrow[r]], 0.f);
    }
    __syncthreads();

    // -- stage c2 -> s_c, c2b -> s_bias --
    for (int e = tid; e < LL * LL; e += NT) {
      int q = e / LL;
      s_c[q * LDC + (e - q * LL)] = c2w[i * LL * LL + e];
    }
    if (tid < LL) s_bias[tid] = c2b[i * LL + tid];
    __syncthreads();

    // -- ff = c2@h + c2b + att, *mask, LN fused -> s_x --
    {
      float f0[NR];
#pragma unroll
      for (int r = 0; r < NR; ++r) f0[r] = s_x[qoff[r] + ln];  // att residual
#pragma unroll 2
      for (int j = 0; j < 48; j += 4) {
        float h0 = s_b[j * LD + ln];
        float h1 = s_b[(j + 1) * LD + ln];
        float h2 = s_b[(j + 2) * LD + ln];
        float h3 = s_b[(j + 3) * LD + ln];
#pragma unroll
        for (int r = 0; r < NR; ++r) {
          float4 cv = ld4(&s_c[coff[r] + j]);
          f0[r] = fmaf(cv.x, h0, fmaf(cv.y, h1, fmaf(cv.z, h2, fmaf(cv.w, h3, f0[r]))));
        }
      }
      {
        float h0 = s_b[48 * LD + ln];
        float h1 = s_b[49 * LD + ln];
#pragma unroll
        for (int r = 0; r < NR; ++r) {
          float2 cv = ld2(&s_c[coff[r] + 48]);
          f0[r] = fmaf(cv.x, h0, fmaf(cv.y, h1, f0[r]));
        }
      }
#pragma unroll
      for (int r = 0; r < NR; ++r) {
        float v = (f0[r] + s_bias[qrow[r]]) * s_mask[qrow[r]];
        float o = rowln(v);
        if (qok[r]) s_x[qoff[r] + ln] = o;
      }
    }
    __syncthreads();
  }

  // ---- gating + output: one wave per (pos/neg, l) row ----
  float g2c = s_scal[0];
  float gloc = s_glo[ln];
#pragma unroll 1
  for (int row = wv; row < 2 * LL; row += NW) {
    int sgn = row >= LL;
    int l = row - sgn * LL;
    int u = user_items[b * LL + l];
    int it = sgn ? neg_items[b * LL + l] : pos_items[b * LL + l];
    float ie_d = item_emb[(size_t)u * DD + ln];
    float mi_d = item_emb[(size_t)it * DD + ln];
    float logit = wsum(ie_d * s_gw[ln] + mi_d * s_gw[128 + ln]) + g2c;
    float sg = 1.f / (1.f + expf(-logit));
    float g = 1.f / (1.f + expf(-sg));  // sigmoid(sigmoid(logit))
    float od = (s_x[l * LD + ln] * g + gloc * (1.f - g)) * s_mask[l];
    float o = rowln(od);
    float res = wsum(o * mi_d);
    if (ln == 0) out[(sgn * NB + b) * LL + l] = res;
  }
}

extern "C" void kernel_launch(void* const* d_in, const int* in_sizes, int n_in,
                              void* d_out, int out_size, void* d_ws, size_t ws_size,
                              hipStream_t stream) {
  const int* user_items = (const int*)d_in[0];
  const int* pos_items = (const int*)d_in[1];
  const int* neg_items = (const int*)d_in[2];
  const float* pmask = (const float*)d_in[3];
  const float* item_emb = (const float*)d_in[4];
  const float* pos_emb = (const float*)d_in[5];
  const float* Qs = (const float*)d_in[6];
  const float* Ks = (const float*)d_in[7];
  const float* Vs = (const float*)d_in[8];
  const float* c1w = (const float*)d_in[9];
  const float* c1b = (const float*)d_in[10];
  const float* c2w = (const float*)d_in[11];
  const float* c2b = (const float*)d_in[12];
  const float* query = (const float*)d_in[13];
  const float* Klba = (const float*)d_in[14];
  const float* Vlba = (const float*)d_in[15];
  const float* l1w = (const float*)d_in[16];
  const float* l1b = (const float*)d_in[17];
  const float* l2w = (const float*)d_in[18];
  const float* l2b = (const float*)d_in[19];
  const float* gw = (const float*)d_in[20];
  const float* gb = (const float*)d_in[21];
  float* out = (float*)d_out;

  fissa_kernel<<<dim3(NB), dim3(NT), 0, stream>>>(
      user_items, pos_items, neg_items, pmask, item_emb, pos_emb, Qs, Ks, Vs,
      c1w, c1b, c2w, c2b, query, Klba, Vlba, l1w, l1b, l2w, l2b, gw, gb, out);
}

// Round 10
// 352.277 us; speedup vs baseline: 1.2917x; 1.0104x over previous
//
#include <hip/hip_runtime.h>

// FISSA forward, MI355X. R10 = R9 (1024-thread blocks, 16 waves, NR=4,
// 2 blocks/CU x 32 waves/CU, 2.0 residency rounds) with the VGPR budget fixed:
// __launch_bounds__(1024,8) made the compiler cap VGPR at 32 -> 74 MB scratch
// spill (R9). amdgpu_waves_per_eu(8) has the documented LLVM semantic:
// VGPR cap = 512/8 = 64, enough for the NR=4 working set (~50) -> no spill.

#define NB 1024
#define NT 1024
#define NW 16
#define LL 50
#define DD 64
#define LD 68   // x/b row stride: rows 16B-aligned for b128 broadcast
#define LDT 51  // Kx^T row stride: odd -> transposed writes 2-way max
#define LDC 52  // score/c1/c2 row stride: rows 16B-aligned for b128 broadcast
#define NR 4
#define NEGV (-4294967295.0f)

__device__ __forceinline__ float wsum(float v) {
#pragma unroll
  for (int m = 32; m >= 1; m >>= 1) v += __shfl_xor(v, m, 64);
  return v;
}
__device__ __forceinline__ float wmax(float v) {
#pragma unroll
  for (int m = 32; m >= 1; m >>= 1) v = fmaxf(v, __shfl_xor(v, m, 64));
  return v;
}
__device__ __forceinline__ float rowln(float v) {
  float m = wsum(v) * (1.f / 64.f);
  float df = v - m;
  float var = wsum(df * df) * (1.f / 64.f);
  return df / sqrtf(var + 1e-8f);
}
__device__ __forceinline__ float2 ld2(const float* p) {
  return *reinterpret_cast<const float2*>(p);
}
__device__ __forceinline__ float4 ld4(const float* p) {
  return *reinterpret_cast<const float4*>(p);
}

__global__ __attribute__((amdgpu_flat_work_group_size(NT, NT),
                          amdgpu_waves_per_eu(8))) void fissa_kernel(
    const int* __restrict__ user_items, const int* __restrict__ pos_items,
    const int* __restrict__ neg_items, const float* __restrict__ pmask,
    const float* __restrict__ item_emb, const float* __restrict__ pos_emb,
    const float* __restrict__ Qs, const float* __restrict__ Ks,
    const float* __restrict__ Vs, const float* __restrict__ c1w,
    const float* __restrict__ c1b, const float* __restrict__ c2w,
    const float* __restrict__ c2b, const float* __restrict__ query,
    const float* __restrict__ Klba, const float* __restrict__ Vlba,
    const float* __restrict__ l1w, const float* __restrict__ l1b,
    const float* __restrict__ l2w, const float* __restrict__ l2b,
    const float* __restrict__ gw, const float* __restrict__ gb,
    float* __restrict__ out) {
  __shared__ __align__(16) float s_x[LL * LD];        // x / att / ff (in-place)
  __shared__ __align__(16) float s_b[LL * LD];        // Qx -> Vx -> h (and LBA-Vx)
  __shared__ __align__(16) float s_kt[DD * LDT + 64]; // Kx^T
  __shared__ __align__(16) float s_c[LL * LDC];       // scores -> c1 -> c2
  __shared__ __align__(16) float s_mask[64], s_qv[64], s_glo[64], s_sm[64],
      s_bias[64], s_gw[192], s_scal[2];

  const int b = blockIdx.x;
  const int tid = threadIdx.x;
  const int wv = tid >> 6, ln = tid & 63;

  int qrow[NR], qoff[NR], coff[NR];
  bool qok[NR];
#pragma unroll
  for (int r = 0; r < NR; ++r) {
    int q = wv + NW * r;
    qok[r] = (q < LL);
    qrow[r] = qok[r] ? q : (LL - 1);
    qoff[r] = qrow[r] * LD;
    coff[r] = qrow[r] * LDC;
  }

  // ---- small params ----
  if (tid < 64) s_mask[tid] = (tid < LL) ? pmask[b * LL + tid] : 0.f;
  else if (tid < 128) s_qv[tid - 64] = query[tid - 64];
  else if (tid < 320) s_gw[tid - 128] = gw[tid - 128];

  // ---- gather + pos emb + mask + LN -> s_x ----
#pragma unroll
  for (int r = 0; r < NR; ++r) {
    int l = qrow[r];
    int u = user_items[b * LL + l];
    float mk = pmask[b * LL + l];
    float v = (item_emb[(size_t)u * DD + ln] + pos_emb[l * DD + ln]) * mk;
    float o = rowln(v);
    if (qok[r]) s_x[qoff[r] + ln] = o;
  }
  __syncthreads();

  // ---- LBA projections: Kx^T -> s_kt, Vx -> s_b (single x-pass) ----
  {
    float akl[NR], avl[NR];
#pragma unroll
    for (int r = 0; r < NR; ++r) { akl[r] = 0.f; avl[r] = 0.f; }
    const float* Kc = Klba + ln;
    const float* Vc = Vlba + ln;
#pragma unroll 2
    for (int kc = 0; kc < DD; kc += 4) {
      float wk0 = Kc[kc * DD], wk1 = Kc[(kc + 1) * DD];
      float wk2 = Kc[(kc + 2) * DD], wk3 = Kc[(kc + 3) * DD];
      float wv0 = Vc[kc * DD], wv1 = Vc[(kc + 1) * DD];
      float wv2 = Vc[(kc + 2) * DD], wv3 = Vc[(kc + 3) * DD];
#pragma unroll
      for (int r = 0; r < NR; ++r) {
        float4 xv = ld4(&s_x[qoff[r] + kc]);
        akl[r] = fmaf(xv.x, wk0, fmaf(xv.y, wk1, fmaf(xv.z, wk2, fmaf(xv.w, wk3, akl[r]))));
        avl[r] = fmaf(xv.x, wv0, fmaf(xv.y, wv1, fmaf(xv.z, wv2, fmaf(xv.w, wv3, avl[r]))));
      }
    }
#pragma unroll
    for (int r = 0; r < NR; ++r)
      if (qok[r]) {
        s_kt[ln * LDT + qrow[r]] = akl[r];
        s_b[qoff[r] + ln] = avl[r];
      }
  }
  __syncthreads();

  // ---- single-wave glo stage ----
  if (wv == 0) {
    float sc = -INFINITY;
    {
      float acc = 0.f;
#pragma unroll 4
      for (int d = 0; d < DD; ++d) acc = fmaf(s_qv[d], s_kt[d * LDT + ln], acc);
      sc = acc;
      if (ln >= LL || s_mask[ln] == 0.f) sc = (ln < LL) ? NEGV : -INFINITY;
    }
    float mx = wmax(sc);
    float e = (ln < LL) ? expf(sc - mx) : 0.f;
    float den = wsum(e);
    if (ln < LL) s_sm[ln] = e / den;  // softmax probs (same-wave DS ordering)
    float acc = 0.f;
#pragma unroll 2
    for (int l = 0; l < LL; ++l) acc = fmaf(s_sm[l], s_b[l * LD + ln], acc);
    float g = rowln(acc);
    float h = fmaxf(l1w[0] * g + l1b[0], 0.f);
    float glo = rowln(l2w[0] * h + l2b[0] + g);
    s_glo[ln] = glo;
    float gs = wsum(glo * s_gw[64 + ln]);
    if (ln == 0) s_scal[0] = gs + gb[0];
  }
  __syncthreads();

  // ---- SAB layers ----
#pragma unroll 1
  for (int i = 0; i < 2; ++i) {
    const float* Qc = Qs + i * DD * DD + ln;
    const float* Kc = Ks + i * DD * DD + ln;
    const float* Vc = Vs + i * DD * DD + ln;

    // -- Qx -> s_b, Kx^T -> s_kt --
    {
      float aq[NR], ak[NR];
#pragma unroll
      for (int r = 0; r < NR; ++r) { aq[r] = 0.f; ak[r] = 0.f; }
#pragma unroll 2
      for (int kc = 0; kc < DD; kc += 4) {
        float wq0 = Qc[kc * DD], wq1 = Qc[(kc + 1) * DD];
        float wq2 = Qc[(kc + 2) * DD], wq3 = Qc[(kc + 3) * DD];
        float wk0 = Kc[kc * DD], wk1 = Kc[(kc + 1) * DD];
        float wk2 = Kc[(kc + 2) * DD], wk3 = Kc[(kc + 3) * DD];
#pragma unroll
        for (int r = 0; r < NR; ++r) {
          float4 xv = ld4(&s_x[qoff[r] + kc]);
          aq[r] = fmaf(xv.x, wq0, fmaf(xv.y, wq1, fmaf(xv.z, wq2, fmaf(xv.w, wq3, aq[r]))));
          ak[r] = fmaf(xv.x, wk0, fmaf(xv.y, wk1, fmaf(xv.z, wk2, fmaf(xv.w, wk3, ak[r]))));
        }
      }
#pragma unroll
      for (int r = 0; r < NR; ++r)
        if (qok[r]) {
          s_b[qoff[r] + ln] = aq[r];
          s_kt[ln * LDT + qrow[r]] = ak[r];
        }
    }
    __syncthreads();

    // -- scores -> s_c (Qx b128 broadcasts, Kx^T stride-1 lane reads) --
    {
      float sc[NR];
#pragma unroll
      for (int r = 0; r < NR; ++r) sc[r] = 0.f;
#pragma unroll 2
      for (int dc = 0; dc < DD; dc += 4) {
        float k0 = s_kt[dc * LDT + ln];
        float k1 = s_kt[(dc + 1) * LDT + ln];
        float k2 = s_kt[(dc + 2) * LDT + ln];
        float k3 = s_kt[(dc + 3) * LDT + ln];
#pragma unroll
        for (int r = 0; r < NR; ++r) {
          float4 qv = ld4(&s_b[qoff[r] + dc]);
          sc[r] = fmaf(qv.x, k0, fmaf(qv.y, k1, fmaf(qv.z, k2, fmaf(qv.w, k3, sc[r]))));
        }
      }
      if (ln < LL) {
        float mk = s_mask[ln];
#pragma unroll
        for (int r = 0; r < NR; ++r)
          if (qok[r]) {
            float v = sc[r] * 0.125f;     // / sqrt(64)
            if (ln > qrow[r]) v = NEGV;   // causal
            if (mk == 0.f) v = NEGV;      // key mask
            v *= s_mask[qrow[r]];         // * padding_mask[q]
            s_c[coff[r] + ln] = v;
          }
      }
    }
    __syncthreads();

    // -- Vx -> s_b (Qx dead) --
    {
      float av[NR];
#pragma unroll
      for (int r = 0; r < NR; ++r) av[r] = 0.f;
#pragma unroll 2
      for (int kc = 0; kc < DD; kc += 4) {
        float wv0 = Vc[kc * DD], wv1 = Vc[(kc + 1) * DD];
        float wv2 = Vc[(kc + 2) * DD], wv3 = Vc[(kc + 3) * DD];
#pragma unroll
        for (int r = 0; r < NR; ++r) {
          float4 xv = ld4(&s_x[qoff[r] + kc]);
          av[r] = fmaf(xv.x, wv0, fmaf(xv.y, wv1, fmaf(xv.z, wv2, fmaf(xv.w, wv3, av[r]))));
        }
      }
#pragma unroll
      for (int r = 0; r < NR; ++r)
        if (qok[r]) s_b[qoff[r] + ln] = av[r];
    }
    __syncthreads();

    // -- att = scores@Vx + x, LN fused -> s_x --
    {
      float at[NR];
#pragma unroll
      for (int r = 0; r < NR; ++r) at[r] = s_x[qoff[r] + ln];  // residual
#pragma unroll 2
      for (int k = 0; k < 48; k += 4) {
        float v0 = s_b[k * LD + ln];
        float v1 = s_b[(k + 1) * LD + ln];
        float v2 = s_b[(k + 2) * LD + ln];
        float v3 = s_b[(k + 3) * LD + ln];
#pragma unroll
        for (int r = 0; r < NR; ++r) {
          float4 sv = ld4(&s_c[coff[r] + k]);
          at[r] = fmaf(sv.x, v0, fmaf(sv.y, v1, fmaf(sv.z, v2, fmaf(sv.w, v3, at[r]))));
        }
      }
      {
        float v0 = s_b[48 * LD + ln];
        float v1 = s_b[49 * LD + ln];
#pragma unroll
        for (int r = 0; r < NR; ++r) {
          float2 sv = ld2(&s_c[coff[r] + 48]);
          at[r] = fmaf(sv.x, v0, fmaf(sv.y, v1, at[r]));
        }
      }
#pragma unroll
      for (int r = 0; r < NR; ++r) {
        float o = rowln(at[r]);
        if (qok[r]) s_x[qoff[r] + ln] = o;
      }
    }
    __syncthreads();

    // -- stage c1 -> s_c, c1b -> s_bias --
    for (int e = tid; e < LL * LL; e += NT) {
      int q = e / LL;
      s_c[q * LDC + (e - q * LL)] = c1w[i * LL * LL + e];
    }
    if (tid < LL) s_bias[tid] = c1b[i * LL + tid];
    __syncthreads();

    // -- h = relu(c1@att + c1b) -> s_b --
    {
      float hh[NR];
#pragma unroll
      for (int r = 0; r < NR; ++r) hh[r] = 0.f;
#pragma unroll 2
      for (int j = 0; j < 48; j += 4) {
        float x0 = s_x[j * LD + ln];
        float x1 = s_x[(j + 1) * LD + ln];
        float x2 = s_x[(j + 2) * LD + ln];
        float x3 = s_x[(j + 3) * LD + ln];
#pragma unroll
        for (int r = 0; r < NR; ++r) {
          float4 cv = ld4(&s_c[coff[r] + j]);
          hh[r] = fmaf(cv.x, x0, fmaf(cv.y, x1, fmaf(cv.z, x2, fmaf(cv.w, x3, hh[r]))));
        }
      }
      {
        float x0 = s_x[48 * LD + ln];
        float x1 = s_x[49 * LD + ln];
#pragma unroll
        for (int r = 0; r < NR; ++r) {
          float2 cv = ld2(&s_c[coff[r] + 48]);
          hh[r] = fmaf(cv.x, x0, fmaf(cv.y, x1, hh[r]));
        }
      }
#pragma unroll
      for (int r = 0; r < NR; ++r)
        if (qok[r]) s_b[qoff[r] + ln] = fmaxf(hh[r] + s_bias[qrow[r]], 0.f);
    }
    __syncthreads();

    // -- stage c2 -> s_c, c2b -> s_bias --
    for (int e = tid; e < LL * LL; e += NT) {
      int q = e / LL;
      s_c[q * LDC + (e - q * LL)] = c2w[i * LL * LL + e];
    }
    if (tid < LL) s_bias[tid] = c2b[i * LL + tid];
    __syncthreads();

    // -- ff = c2@h + c2b + att, *mask, LN fused -> s_x --
    {
      float f0[NR];
#pragma unroll
      for (int r = 0; r < NR; ++r) f0[r] = s_x[qoff[r] + ln];  // att residual
#pragma unroll 2
      for (int j = 0; j < 48; j += 4) {
        float h0 = s_b[j * LD + ln];
        float h1 = s_b[(j + 1) * LD + ln];
        float h2 = s_b[(j + 2) * LD + ln];
        float h3 = s_b[(j + 3) * LD + ln];
#pragma unroll
        for (int r = 0; r < NR; ++r) {
          float4 cv = ld4(&s_c[coff[r] + j]);
          f0[r] = fmaf(cv.x, h0, fmaf(cv.y, h1, fmaf(cv.z, h2, fmaf(cv.w, h3, f0[r]))));
        }
      }
      {
        float h0 = s_b[48 * LD + ln];
        float h1 = s_b[49 * LD + ln];
#pragma unroll
        for (int r = 0; r < NR; ++r) {
          float2 cv = ld2(&s_c[coff[r] + 48]);
          f0[r] = fmaf(cv.x, h0, fmaf(cv.y, h1, f0[r]));
        }
      }
#pragma unroll
      for (int r = 0; r < NR; ++r) {
        float v = (f0[r] + s_bias[qrow[r]]) * s_mask[qrow[r]];
        float o = rowln(v);
        if (qok[r]) s_x[qoff[r] + ln] = o;
      }
    }
    __syncthreads();
  }

  // ---- gating + output: one wave per (pos/neg, l) row ----
  float g2c = s_scal[0];
  float gloc = s_glo[ln];
#pragma unroll 1
  for (int row = wv; row < 2 * LL; row += NW) {
    int sgn = row >= LL;
    int l = row - sgn * LL;
    int u = user_items[b * LL + l];
    int it = sgn ? neg_items[b * LL + l] : pos_items[b * LL + l];
    float ie_d = item_emb[(size_t)u * DD + ln];
    float mi_d = item_emb[(size_t)it * DD + ln];
    float logit = wsum(ie_d * s_gw[ln] + mi_d * s_gw[128 + ln]) + g2c;
    float sg = 1.f / (1.f + expf(-logit));
    float g = 1.f / (1.f + expf(-sg));  // sigmoid(sigmoid(logit))
    float od = (s_x[l * LD + ln] * g + gloc * (1.f - g)) * s_mask[l];
    float o = rowln(od);
    float res = wsum(o * mi_d);
    if (ln == 0) out[(sgn * NB + b) * LL + l] = res;
  }
}

extern "C" void kernel_launch(void* const* d_in, const int* in_sizes, int n_in,
                              void* d_out, int out_size, void* d_ws, size_t ws_size,
                              hipStream_t stream) {
  const int* user_items = (const int*)d_in[0];
  const int* pos_items = (const int*)d_in[1];
  const int* neg_items = (const int*)d_in[2];
  const float* pmask = (const float*)d_in[3];
  const float* item_emb = (const float*)d_in[4];
  const float* pos_emb = (const float*)d_in[5];
  const float* Qs = (const float*)d_in[6];
  const float* Ks = (const float*)d_in[7];
  const float* Vs = (const float*)d_in[8];
  const float* c1w = (const float*)d_in[9];
  const float* c1b = (const float*)d_in[10];
  const float* c2w = (const float*)d_in[11];
  const float* c2b = (const float*)d_in[12];
  const float* query = (const float*)d_in[13];
  const float* Klba = (const float*)d_in[14];
  const float* Vlba = (const float*)d_in[15];
  const float* l1w = (const float*)d_in[16];
  const float* l1b = (const float*)d_in[17];
  const float* l2w = (const float*)d_in[18];
  const float* l2b = (const float*)d_in[19];
  const float* gw = (const float*)d_in[20];
  const float* gb = (const float*)d_in[21];
  float* out = (float*)d_out;

  fissa_kernel<<<dim3(NB), dim3(NT), 0, stream>>>(
      user_items, pos_items, neg_items, pmask, item_emb, pos_emb, Qs, Ks, Vs,
      c1w, c1b, c2w, c2b, query, Klba, Vlba, l1w, l1b, l2w, l2b, gw, gb, out);
}